// Round 6
// baseline (222.552 us; speedup 1.0000x reference)
//
#include <hip/hip_runtime.h>

#define N_TOK  8192
#define KDIM   4096
#define NE     16
#define NSLICE 4                   // coarse k-split: 4 KB of each row per block
#define TB     64                  // tokens per block (= wave width)
#define BKT    256                 // k per tile
#define NTILE  ((KDIM / NSLICE) / BKT)  // 4
#define LSTR   (BKT + 4)           // 260: +4 floats -> conflict-free b128 both sides

// Partial logits. DRAM-burst-aware staging: one wave-instruction reads 1 KB
// CONTIGUOUS from ONE token row (64 lanes x float4) -> full page burst per
// activation. (R3/R4/R5 all capped at ~2.5 TB/s because k-split sharded each
// row into 256 B/page-visit grains; 1 KB/activation lifts the tRC cap.)
// Compute keeps lane<->token so gate rows are wave-uniform s_loads.
__global__ __launch_bounds__(256, 2)
void router_partial(const float* __restrict__ x, const float* __restrict__ gate,
                    float* __restrict__ ws) {
  __shared__ __align__(16) float tile[TB * LSTR];   // 66560 B -> 2 blocks/CU
  const int tid  = threadIdx.x;
  const int lane = tid & 63;
  const int w    = __builtin_amdgcn_readfirstlane(tid >> 6);  // SGPR
  const int g    = blockIdx.x >> 2;          // token group (128)
  const int s    = blockIdx.x & 3;           // k-quarter (4)
  const int t0   = g * TB;
  const int kbase = s * (KDIM / NSLICE);     // s * 1024

  float acc[NE];
#pragma unroll
  for (int e = 0; e < NE; ++e) acc[e] = 0.f;

  for (int tl = 0; tl < NTILE; ++tl) {
    const int k0 = kbase + tl * BKT;
    __syncthreads();                         // prev compute done before overwrite
    // stage 64 rows x 1 KB; wave w does rows [16w,16w+16) in two 8-row groups.
    // Constant-index v[8] after unroll -> SROA to registers (no scratch).
#pragma unroll
    for (int h = 0; h < 2; ++h) {
      float4 v[8];
#pragma unroll
      for (int r = 0; r < 8; ++r) {          // 8 independent 1 KB row-bursts
        int row = w * 16 + h * 8 + r;
        v[r] = *(const float4*)(x + (size_t)(t0 + row) * KDIM + k0 + lane * 4);
      }
#pragma unroll
      for (int r = 0; r < 8; ++r) {          // b128, banks (4row+4lane)%32: free
        int row = w * 16 + h * 8 + r;
        *(float4*)(tile + row * LSTR + lane * 4) = v[r];
      }
    }
    __syncthreads();
    // compute: lane = token, wave w covers k-cols [w*64, w*64+64) of the tile
#pragma unroll
    for (int c = 0; c < 16; ++c) {
      float4 xv4 = *(const float4*)(tile + lane * LSTR + w * 64 + c * 4);
      const float xv[4] = {xv4.x, xv4.y, xv4.z, xv4.w};
      const int kk = k0 + w * 64 + c * 4;
#pragma unroll
      for (int m = 0; m < 4; ++m) {
        const float* grow = gate + (size_t)(kk + m) * NE;  // uniform -> s_load
#pragma unroll
        for (int e = 0; e < NE; ++e) acc[e] = fmaf(xv[m], grow[e], acc[e]);
      }
    }
  }

  // cross-wave reduction of the 4 k-subranges, one ws float4 per thread
  __syncthreads();                           // all waves done with tile reads
  float* red = tile;                         // reuse as [256][17]
#pragma unroll
  for (int e = 0; e < NE; ++e) red[(w * 64 + lane) * 17 + e] = acc[e];
  __syncthreads();
  {
    int p0 = tid * 4;                        // 1024 (token,e) pairs, 4/thread
    int t  = p0 >> 4, e0 = p0 & 15;
    float v[4];
#pragma unroll
    for (int j = 0; j < 4; ++j) {
      float sum = 0.f;
#pragma unroll
      for (int ww = 0; ww < 4; ++ww) sum += red[(ww * 64 + t) * 17 + e0 + j];
      v[j] = sum;
    }
    *(float4*)(ws + ((size_t)s * N_TOK + (t0 + t)) * NE + e0) =
        make_float4(v[0], v[1], v[2], v[3]);
  }
}

// Sum 4 slice partials, top-2 (earliest-index tie-break = jax top_k),
// sigmoid, scatter into (E,N) scores; token_indices[e][t] = t (as float).
__global__ __launch_bounds__(256)
void router_finalize(const float* __restrict__ ws, float* __restrict__ out) {
  int t = blockIdx.x * 256 + threadIdx.x;
  float l[NE];
#pragma unroll
  for (int e = 0; e < NE; ++e) l[e] = 0.f;
#pragma unroll
  for (int s = 0; s < NSLICE; ++s) {
    const float4* row = (const float4*)(ws + ((size_t)s * N_TOK + t) * NE);
    float4 r0 = row[0], r1 = row[1], r2 = row[2], r3 = row[3];
    l[0]  += r0.x; l[1]  += r0.y; l[2]  += r0.z; l[3]  += r0.w;
    l[4]  += r1.x; l[5]  += r1.y; l[6]  += r1.z; l[7]  += r1.w;
    l[8]  += r2.x; l[9]  += r2.y; l[10] += r2.z; l[11] += r2.w;
    l[12] += r3.x; l[13] += r3.y; l[14] += r3.z; l[15] += r3.w;
  }
  int i1 = 0; float v1 = l[0];
#pragma unroll
  for (int e = 1; e < NE; ++e) { if (l[e] > v1) { v1 = l[e]; i1 = e; } }
  int i2 = -1; float v2 = -1e30f;
#pragma unroll
  for (int e = 0; e < NE; ++e) { if (e != i1 && l[e] > v2) { v2 = l[e]; i2 = e; } }
  float s1 = 1.f / (1.f + __expf(-v1));
  float s2 = 1.f / (1.f + __expf(-v2));
  float* scores = out;
  float* tix    = out + (size_t)NE * N_TOK;
  float tf = (float)t;
#pragma unroll
  for (int e = 0; e < NE; ++e) {             // coalesced across lanes per e
    scores[(size_t)e * N_TOK + t] = (e == i1) ? s1 : ((e == i2) ? s2 : 0.f);
    tix[(size_t)e * N_TOK + t]    = tf;
  }
}

extern "C" void kernel_launch(void* const* d_in, const int* in_sizes, int n_in,
                              void* d_out, int out_size, void* d_ws, size_t ws_size,
                              hipStream_t stream) {
  const float* x    = (const float*)d_in[0];
  const float* gate = (const float*)d_in[1];
  float* out = (float*)d_out;
  float* ws  = (float*)d_ws;   // needs NSLICE*N_TOK*NE*4 = 2 MB
  router_partial<<<dim3(N_TOK / TB * NSLICE), dim3(256), 0, stream>>>(x, gate, ws);
  router_finalize<<<dim3(N_TOK / 256), dim3(256), 0, stream>>>(ws, out);
}

// Round 7
// 201.924 us; speedup vs baseline: 1.1022x; 1.1022x over previous
//
#include <hip/hip_runtime.h>

#define N_TOK  8192
#define KDIM   4096
#define NE     16
#define NSLICE 4                   // k-quarter per block -> 512 blocks, 2/CU
#define TB     64                  // tokens per block (= wave width)
#define WF     128                 // window = 128 floats (512 B per row)
#define NTILE  8                   // 8 windows per block = 1024 k
#define NWIN   32                  // 32 windows cover the 16 KB row

// async global->LDS DMA, 16 B/lane; LDS dest = lptr + lane*16 (uniform base)
__device__ __forceinline__ void async_ld16(const float* g, float* l) {
  __builtin_amdgcn_global_load_lds(
      (const __attribute__((address_space(1))) void*)g,
      (__attribute__((address_space(3))) void*)l, 16, 0, 0);
}

// Partial logits. R6 counters: 90us, VALUBusy 8%, 775 GB/s -> waves idle on
// (1) barrier-serialized stage/compute, (2) HBM channel aliasing from x's
// 16 KB power-of-2 row stride (all same-s blocks hammer one channel subset).
// Fixes: (a) global_load_lds double-buffer, one tile ahead -> 32 KB/block in
// flight during compute, no staging VGPRs (kills the R2/R3 scratch trap);
// (b) XOR swizzle slot=col^(row&7) -> conflict-free b128 reads, no padding
// (DMA requires lane-linear LDS); (c) per-block window rotation
// win = ((s+g)&3) + 4*((tl+g)&7): co-resident blocks cover all 32 windows of
// the alias period -> uniform channel load. Gate rows stay wave-uniform
// (win is block-uniform) -> scalar s_loads.
__global__ __launch_bounds__(256)
void router_partial(const float* __restrict__ x, const float* __restrict__ gate,
                    float* __restrict__ ws) {
  __shared__ __align__(16) float lds[2 * TB * WF];   // 2 x 32 KB = 64 KB -> 2/CU
  const int tid  = threadIdx.x;
  const int lane = tid & 63;
  const int w    = __builtin_amdgcn_readfirstlane(tid >> 6);
  const int g    = blockIdx.x >> 2;          // token group (128)
  const int s    = blockIdx.x & 3;           // k-quarter tag (4)
  const int t0   = g * TB;

  float acc[NE];
#pragma unroll
  for (int e = 0; e < NE; ++e) acc[e] = 0.f;

  // per-wave DMA of 16 rows (2 rows per 1 KB instr): lanes 0-31 -> row 2j,
  // lanes 32-63 -> row 2j+1; source col XOR-swizzled within the 512 B window.
  const int rhalf = lane >> 5;               // row parity within DMA
  const int c32   = lane & 31;               // slot within row (16 B units)
#define STAGE(bufp, win)                                                       \
  {                                                                            \
    const int kw = (win) * WF;                                                 \
    _Pragma("unroll")                                                          \
    for (int j = 0; j < 8; ++j) {                                              \
      int row  = w * 16 + 2 * j + rhalf;                                       \
      int col4 = c32 ^ (row & 7);                                              \
      const float* gp = x + (size_t)(t0 + row) * KDIM + kw + col4 * 4;         \
      float* lp = (bufp) + (w * 16 + 2 * j) * WF;  /* wave-uniform base */     \
      async_ld16(gp, lp);                                                      \
    }                                                                          \
  }

  const int sw = lane & 7;
  {
    int win0 = ((s + g) & 3) + 4 * (g & 7);
    STAGE(lds, win0);
  }
  for (int tl = 0; tl < NTILE; ++tl) {
    __builtin_amdgcn_s_waitcnt(0x0F70);      // vmcnt(0): this tile's DMAs done
    __syncthreads();                         // all waves: prev compute done too
    float* cur = lds + (tl & 1) * (TB * WF);
    if (tl + 1 < NTILE) {
      int winn = ((s + g) & 3) + 4 * ((tl + 1 + g) & 7);
      float* nxt = lds + ((tl + 1) & 1) * (TB * WF);
      STAGE(nxt, winn);                      // in flight through compute below
    }
    const int win = ((s + g) & 3) + 4 * ((tl + g) & 7);
    const float* gb = gate + (size_t)(win * WF + w * 32) * NE;
#pragma unroll
    for (int c = 0; c < 8; ++c) {            // wave w: float4 cols [w*8, w*8+8)
      int slot = (w * 8 + c) ^ sw;           // undo swizzle for my row (=lane)
      float4 xv4 = *(const float4*)(cur + lane * WF + slot * 4);
      const float xv[4] = {xv4.x, xv4.y, xv4.z, xv4.w};
#pragma unroll
      for (int m = 0; m < 4; ++m) {
        const float* grow = gb + (size_t)(c * 4 + m) * NE;  // uniform -> s_load
#pragma unroll
        for (int e = 0; e < NE; ++e) acc[e] = fmaf(xv[m], grow[e], acc[e]);
      }
    }
  }

  // cross-wave reduction (4 k-strips), one ws float4 per thread
  __syncthreads();
  float* red = lds;                          // reuse as [256][17]
#pragma unroll
  for (int e = 0; e < NE; ++e) red[(w * 64 + lane) * 17 + e] = acc[e];
  __syncthreads();
  {
    int p0 = tid * 4;                        // 1024 (token,e) pairs, 4/thread
    int t  = p0 >> 4, e0 = p0 & 15;
    float v[4];
#pragma unroll
    for (int j = 0; j < 4; ++j) {
      float sum = 0.f;
#pragma unroll
      for (int ww = 0; ww < 4; ++ww) sum += red[(ww * 64 + t) * 17 + e0 + j];
      v[j] = sum;
    }
    *(float4*)(ws + ((size_t)s * N_TOK + (t0 + t)) * NE + e0) =
        make_float4(v[0], v[1], v[2], v[3]);
  }
}

// Sum 4 slice partials, top-2 (earliest-index tie-break = jax top_k),
// sigmoid, scatter into (E,N) scores; token_indices[e][t] = t (as float).
__global__ __launch_bounds__(256)
void router_finalize(const float* __restrict__ ws, float* __restrict__ out) {
  int t = blockIdx.x * 256 + threadIdx.x;
  float l[NE];
#pragma unroll
  for (int e = 0; e < NE; ++e) l[e] = 0.f;
#pragma unroll
  for (int s = 0; s < NSLICE; ++s) {
    const float4* row = (const float4*)(ws + ((size_t)s * N_TOK + t) * NE);
    float4 r0 = row[0], r1 = row[1], r2 = row[2], r3 = row[3];
    l[0]  += r0.x; l[1]  += r0.y; l[2]  += r0.z; l[3]  += r0.w;
    l[4]  += r1.x; l[5]  += r1.y; l[6]  += r1.z; l[7]  += r1.w;
    l[8]  += r2.x; l[9]  += r2.y; l[10] += r2.z; l[11] += r2.w;
    l[12] += r3.x; l[13] += r3.y; l[14] += r3.z; l[15] += r3.w;
  }
  int i1 = 0; float v1 = l[0];
#pragma unroll
  for (int e = 1; e < NE; ++e) { if (l[e] > v1) { v1 = l[e]; i1 = e; } }
  int i2 = -1; float v2 = -1e30f;
#pragma unroll
  for (int e = 0; e < NE; ++e) { if (e != i1 && l[e] > v2) { v2 = l[e]; i2 = e; } }
  float s1 = 1.f / (1.f + __expf(-v1));
  float s2 = 1.f / (1.f + __expf(-v2));
  float* scores = out;
  float* tix    = out + (size_t)NE * N_TOK;
  float tf = (float)t;
#pragma unroll
  for (int e = 0; e < NE; ++e) {             // coalesced across lanes per e
    scores[(size_t)e * N_TOK + t] = (e == i1) ? s1 : ((e == i2) ? s2 : 0.f);
    tix[(size_t)e * N_TOK + t]    = tf;
  }
}

extern "C" void kernel_launch(void* const* d_in, const int* in_sizes, int n_in,
                              void* d_out, int out_size, void* d_ws, size_t ws_size,
                              hipStream_t stream) {
  const float* x    = (const float*)d_in[0];
  const float* gate = (const float*)d_in[1];
  float* out = (float*)d_out;
  float* ws  = (float*)d_ws;   // needs NSLICE*N_TOK*NE*4 = 2 MB
  router_partial<<<dim3(N_TOK / TB * NSLICE), dim3(256), 0, stream>>>(x, gate, ws);
  router_finalize<<<dim3(N_TOK / 256), dim3(256), 0, stream>>>(ws, out);
}